// Round 13
// baseline (95.218 us; speedup 1.0000x reference)
//
#include <hip/hip_runtime.h>
#include <hip/hip_bf16.h>

// Dense softmax attention (NO 1/sqrt(D) scale). B=4, L=2048, H=8, D=64,
// fp32 in/out, layout (B, L, H, D).
// Round 12: OCCUPANCY 4 -> 8 waves/SIMD.
//  - r7/r9/r10 all 62-64us under 3 schedules; r11 (fewer MFMA slots)
//    regressed -> latency/TLP-bound, not pipe-bound. Grid 512 x 8 waves
//    = 4 waves/SIMD was the cap.
//  - New geometry: 1024-thr blocks, 16 waves = 8 qsub x 2 ks, 16 q-rows
//    per wave (single m-tile). 512 blocks x 16 waves = 8192 waves =
//    8/SIMD, 2 blocks/CU (2048 thr, 90KB LDS). Requires <=64 VGPR:
//    __launch_bounds__(1024, 8) + kg-sliced JIT fragment reads + small
//    per-wave state (o[4]+lsum+qf[2] = 28 persistent regs).
//  - Staging halved per thread: tid<512 stages K (one b128), tid>=512
//    stages V (4 u32). All LDS reads precede all LDS writes per tile.
//  - Math identical to r10 (passed, 0.03125): f16 QK^T swapped mfma(K,Q),
//    log2e in Q, exp2, K16 bf16 PV direct-feed, ones-MFMA lsum, exact
//    2-way k-split merge, XCD swizzle, dbuf one-barrier loop.

#define B_ 4
#define L_ 2048
#define H_ 8
#define D_ 64
#define RST_ 512               // floats between consecutive l (H_*D_)
#define QW_ 16                 // q rows per wave
#define QB_ 128                // 8 qsub * 16
#define KT_ 64
#define NT_ (L_ / KT_)         // 32
#define RS_ 88                 // K/V LDS row stride, 2B units (176B)
#define OTS_ 68                // epilogue transpose row stride, f32
#define SCW_ 18                // merge scratch words/lane (17 used)
#define LOG2E_ 1.44269504088896f

// smem: Kf0 0 | Kf1 11264 | Vt0 22528 | Vt1 33792 ; total 45056
// epilogue overlay: Sc[8 qsub][64 lanes][SCW_] f32 = 36864B;
//                   Ot reuses each qsub's own Sc region in-place (4608B >= 4352B)
#define SMEM_BYTES 45056

typedef _Float16 f16x8 __attribute__((ext_vector_type(8)));
typedef short    s16x4 __attribute__((ext_vector_type(4)));
typedef float    f32x4 __attribute__((ext_vector_type(4)));

__device__ __forceinline__ unsigned pk_bf16(float a, float b) {
    const __bf16 x = (__bf16)a, y = (__bf16)b;
    return ((unsigned)__builtin_bit_cast(unsigned short, y) << 16) |
           (unsigned)__builtin_bit_cast(unsigned short, x);
}

__device__ __forceinline__ f32x4 mfma16_bf16(s16x4 a, s16x4 b, f32x4 c) {
    return __builtin_amdgcn_mfma_f32_16x16x16bf16_1k(a, b, c, 0, 0, 0);
}

__global__ __launch_bounds__(1024, 8) void attn_occ8(
    const float* __restrict__ Qg, const float* __restrict__ Kg,
    const float* __restrict__ Vg, float* __restrict__ Og)
{
    __shared__ __align__(16) char smem[SMEM_BYTES];
    _Float16* Kf0 = (_Float16*)smem;
    _Float16* Kf1 = (_Float16*)(smem + 11264);
    __bf16*   Vt0 = (__bf16*)(smem + 22528);
    __bf16*   Vt1 = (__bf16*)(smem + 33792);
    float*    Sc  = (float*)smem;                   // epilogue overlay

    const int tid  = threadIdx.x;
    const int w    = tid >> 6;          // 0..15
    const int qsub = w & 7;
    const int ks   = w >> 3;            // key-half 0/1
    const int ln   = tid & 15;
    const int lg   = (tid >> 4) & 3;

    // XCD-aware bijective swizzle (512 % 8 == 0)
    const int blk   = (blockIdx.x & 7) * 64 + (blockIdx.x >> 3);
    const int qtile = blk & (L_ / QB_ - 1);
    const int bh    = blk >> 4;
    const int h     = bh & (H_ - 1);
    const int b     = bh >> 3;

    const size_t bhbase = (size_t)b * (L_ * H_ * D_) + (size_t)h * D_;
    const int    qbase  = qtile * QB_ + qsub * QW_;

    // ---- Q fragments f16 (16 rows), pre-scaled by log2e ----
    f16x8 qf[2];
#pragma unroll
    for (int dc = 0; dc < 2; ++dc) {
        const float* src = Qg + bhbase
            + (size_t)(qbase + ln) * RST_ + dc * 32 + lg * 8;
        const float4 a = ((const float4*)src)[0];
        const float4 c = ((const float4*)src)[1];
        f16x8 f;
        f[0] = (_Float16)(a.x * LOG2E_); f[1] = (_Float16)(a.y * LOG2E_);
        f[2] = (_Float16)(a.z * LOG2E_); f[3] = (_Float16)(a.w * LOG2E_);
        f[4] = (_Float16)(c.x * LOG2E_); f[5] = (_Float16)(c.y * LOG2E_);
        f[6] = (_Float16)(c.z * LOG2E_); f[7] = (_Float16)(c.w * LOG2E_);
        qf[dc] = f;
    }

    f32x4 o[4];             // O^T partial: lane holds d=dg*16+lg*4+r, q=ln
    f32x4 lsum;
    lsum = (f32x4){0.f, 0.f, 0.f, 0.f};
#pragma unroll
    for (int dg = 0; dg < 4; ++dg) o[dg] = (f32x4){0.f, 0.f, 0.f, 0.f};

    s16x4 ones4;
#pragma unroll
    for (int j = 0; j < 4; ++j) ones4[j] = (short)0x3F80;   // bf16 1.0

    // ---- staging: threads 0-511 stage K, 512-1023 stage V ----
    const bool isK = (tid < 512);               // wave-uniform
    const int  kt_ = tid & 511;
    const int  krow = kt_ >> 3;                 // K: 0..63
    const int  kd8  = (kt_ & 7) * 8;            // K: d base 0..56
    const int  vkp  = (kt_ & 31) * 2;           // V: key pair 0..62
    const int  vdb  = (kt_ >> 5) * 4;           // V: d base 0..60

    const float* gp = isK
        ? (Kg + bhbase + (size_t)krow * RST_ + kd8)
        : (Vg + bhbase + (size_t)vkp * RST_ + vdb);
    const int soff = isK ? 4 : RST_;            // second-float4 offset

    float4 s0, s1;                              // named stage regs (spill-proof)

    auto issue = [&]() {
        s0 = ((const float4*)gp)[0];
        s1 = *(const float4*)(gp + soff);
        gp += (size_t)KT_ * RST_;
    };
    auto writeKV = [&](_Float16* Kf, __bf16* Vt) {
        if (isK) {
            f16x8 kw;
            kw[0] = (_Float16)s0.x; kw[1] = (_Float16)s0.y;
            kw[2] = (_Float16)s0.z; kw[3] = (_Float16)s0.w;
            kw[4] = (_Float16)s1.x; kw[5] = (_Float16)s1.y;
            kw[6] = (_Float16)s1.z; kw[7] = (_Float16)s1.w;
            *(f16x8*)&Kf[krow * RS_ + kd8] = kw;
        } else {
            *(unsigned*)&Vt[(vdb + 0) * RS_ + vkp] = pk_bf16(s0.x, s1.x);
            *(unsigned*)&Vt[(vdb + 1) * RS_ + vkp] = pk_bf16(s0.y, s1.y);
            *(unsigned*)&Vt[(vdb + 2) * RS_ + vkp] = pk_bf16(s0.z, s1.z);
            *(unsigned*)&Vt[(vdb + 3) * RS_ + vkp] = pk_bf16(s0.w, s1.w);
        }
    };

    // ---- per-tile compute: kg-sliced, JIT fragment reads (low reg peak) ----
    auto computeT = [&](const _Float16* Kf, const __bf16* Vt) {
#pragma unroll
        for (int kg = 0; kg < 2; ++kg) {
            const int krow0 = (ks * 32 + kg * 16 + ln) * RS_;
            const f16x8 ka = *(const f16x8*)&Kf[krow0 + lg * 8];
            const f16x8 kb = *(const f16x8*)&Kf[krow0 + 32 + lg * 8];
            const int vcol = ks * 32 + kg * 16 + lg * 4;
            const s16x4 v0 = *(const s16x4*)&Vt[(0 * 16 + ln) * RS_ + vcol];
            const s16x4 v1 = *(const s16x4*)&Vt[(1 * 16 + ln) * RS_ + vcol];
            const s16x4 v2 = *(const s16x4*)&Vt[(2 * 16 + ln) * RS_ + vcol];
            const s16x4 v3 = *(const s16x4*)&Vt[(3 * 16 + ln) * RS_ + vcol];

            f32x4 st = (f32x4){0.f, 0.f, 0.f, 0.f};
            __builtin_amdgcn_s_setprio(1);
            st = __builtin_amdgcn_mfma_f32_16x16x32_f16(ka, qf[0], st, 0, 0, 0);
            st = __builtin_amdgcn_mfma_f32_16x16x32_f16(kb, qf[1], st, 0, 0, 0);
            __builtin_amdgcn_s_setprio(0);

            const float e0 = __builtin_amdgcn_exp2f(st[0]);
            const float e1 = __builtin_amdgcn_exp2f(st[1]);
            const float e2 = __builtin_amdgcn_exp2f(st[2]);
            const float e3 = __builtin_amdgcn_exp2f(st[3]);
            union { unsigned u[2]; s16x4 v; } pu;
            pu.u[0] = pk_bf16(e0, e1);
            pu.u[1] = pk_bf16(e2, e3);
            const s16x4 pf = pu.v;

            __builtin_amdgcn_s_setprio(1);
            lsum = mfma16_bf16(ones4, pf, lsum);
            o[0] = mfma16_bf16(v0, pf, o[0]);
            o[1] = mfma16_bf16(v1, pf, o[1]);
            o[2] = mfma16_bf16(v2, pf, o[2]);
            o[3] = mfma16_bf16(v3, pf, o[3]);
            __builtin_amdgcn_s_setprio(0);
        }
    };

    // ---- prologue: tile0 -> buf0, tile1 in stage regs ----
    issue();                    // tile 0
    writeKV(Kf0, Vt0);
    issue();                    // tile 1
    __syncthreads();

    // ---- main loop: ONE barrier/tile; reads precede writes ----
    for (int t = 0; t < NT_; t += 2) {
        computeT(Kf0, Vt0);                     // tile t (reads only)
        writeKV(Kf1, Vt1);                      // stage = tile t+1 (t+1 <= 31)
        if (t + 2 < NT_) issue();               // tile t+2
        __syncthreads();
        computeT(Kf1, Vt1);                     // tile t+1
        if (t + 2 < NT_) writeKV(Kf0, Vt0);     // stage = tile t+2
        if (t + 3 < NT_) issue();               // tile t+3
        __syncthreads();
    }

    // ---- merge epilogue (2-way k-split partials add exactly) ----
    const int lane = tid & 63;
    if (ks == 1) {
        float* sc = &Sc[(qsub * 64 + lane) * SCW_];
#pragma unroll
        for (int dg = 0; dg < 4; ++dg)
#pragma unroll
            for (int r = 0; r < 4; ++r)
                sc[dg * 4 + r] = o[dg][r];
        sc[16] = lsum[0];
    }
    __syncthreads();
    if (ks == 0) {
        const float* sc = &Sc[(qsub * 64 + lane) * SCW_];
        float po[4][4];
#pragma unroll
        for (int dg = 0; dg < 4; ++dg)
#pragma unroll
            for (int r = 0; r < 4; ++r)
                po[dg][r] = o[dg][r] + sc[dg * 4 + r];
        const float linv = 1.0f / (lsum[0] + sc[16]);

        // in-place transpose buffer over this qsub's Sc region (read done)
        float* Ot = (float*)(smem + qsub * (64 * SCW_ * 4));
        const int qr = lane >> 2;
        const int ch = lane & 3;
#pragma unroll
        for (int dg = 0; dg < 4; ++dg) {
#pragma unroll
            for (int i = 0; i < 2; ++i) {
                float2 pr;
                pr.x = po[dg][2 * i]     * linv;
                pr.y = po[dg][2 * i + 1] * linv;
                *(float2*)&Ot[ln * OTS_ + dg * 16 + lg * 4 + 2 * i] = pr;
            }
        }
#pragma unroll
        for (int p = 0; p < 4; ++p) {
            const float4 vo = *(const float4*)&Ot[qr * OTS_ + ch * 4 + p * 16];
            *(float4*)(Og + bhbase
                + (size_t)(qbase + qr) * RST_ + ch * 4 + p * 16) = vo;
        }
    }
}

extern "C" void kernel_launch(void* const* d_in, const int* in_sizes, int n_in,
                              void* d_out, int out_size, void* d_ws, size_t ws_size,
                              hipStream_t stream) {
    const float* Q = (const float*)d_in[0];
    const float* K = (const float*)d_in[1];
    const float* V = (const float*)d_in[2];
    float* O = (float*)d_out;

    const int grid = B_ * H_ * (L_ / QB_);   // 512 blocks x 1024 threads
    attn_occ8<<<grid, 1024, 0, stream>>>(Q, K, V, O);
}